// Round 4
// baseline (254.137 us; speedup 1.0000x reference)
//
#include <hip/hip_runtime.h>
#include <stdint.h>

#define IN_DIM  32768
#define OUT_DIM 32768
#define BATCH   1024
#define NT      1024
#define GRID    256                   // 1 block per CU, exact fill, no tail
#define RPB     (BATCH / GRID)        // 4 rows per block
#define ITER    (OUT_DIM / 4 / NT)    // 8 output groups (4 outputs each) per row
#define SITER   (IN_DIM / 4 / NT)     // 8 stage chunks (4 floats each) per row
#define LDS_BYTES (2 * IN_DIM * 2)    // two 64 KiB fp16 row buffers (double-buffer)

typedef float  fvec4 __attribute__((ext_vector_type(4)));
typedef __fp16 h2v   __attribute__((ext_vector_type(2)));   // cvt_pkrtz return type

__device__ __forceinline__ uint32_t pack2_f16(float lo, float hi) {
    h2v h = __builtin_amdgcn_cvt_pkrtz(lo, hi);
    return __builtin_bit_cast(uint32_t, h);
}
__device__ __forceinline__ float ldrow(const uint16_t* row, uint32_t byteoff) {
    __fp16 h = *(const __fp16*)((const char*)row + byteoff);
    return (float)h;
}
__device__ __forceinline__ float sel(uint32_t flag, float v) {
    return flag ? 1.0f - v : v;
}

// packed layout: low16 = (idx_a<<1) | flagA ; high16 = (idx_b<<1) | flagB
// idx<<1 is directly the LDS byte offset of the fp16 element.
__global__ void pack_meta(const int* __restrict__ idx_a,
                          const int* __restrict__ idx_b,
                          const float* __restrict__ logits,
                          uint32_t* __restrict__ packed) {
    int j = blockIdx.x * blockDim.x + threadIdx.x;
    if (j >= OUT_DIM) return;
    uint32_t ia = (((uint32_t)idx_a[j]) << 1) & 0xFFFFu;
    uint32_t ib = (((uint32_t)idx_b[j]) << 1) & 0xFFFFu;
    if (logits[2 * j + 0] > 0.0f) ia |= 1u;   // sigmoid(l)>0.5 <=> l>0
    if (logits[2 * j + 1] > 0.0f) ib |= 1u;
    packed[j] = ia | (ib << 16);
}

// Persistent producer-consumer: 1 block/CU, 4 rows/block, double-buffered LDS.
// Steady state: prefetch-loads(row k+1) and output-stores(row k) are in flight
// SIMULTANEOUSLY -- breaks the phase-exclusive memory pattern that pinned all
// previous versions at 82 us. Meta is register-resident across all 4 rows.
__global__ __launch_bounds__(NT, 4) void logic_gather(
        const float* __restrict__ x,
        const uint32_t* __restrict__ packed,
        float* __restrict__ out) {
    extern __shared__ __align__(16) uint16_t lds[];   // [2][IN_DIM] fp16
    uint16_t* const buf0 = lds;
    uint16_t* const buf1 = lds + IN_DIM;
    const int t = threadIdx.x;
    const int b = blockIdx.x;

    // ---- meta: load once, reuse for all RPB rows (32 VGPRs, hot in L3)
    const uint4* __restrict__ pk = (const uint4*)packed;
    uint4 p[ITER];
#pragma unroll
    for (int i = 0; i < ITER; ++i) p[i] = pk[i * NT + t];

    // ---- stage row 0 into buf0 (the only fully-exposed stage)
    {
        const float4* __restrict__ xr = (const float4*)(x + (size_t)b * IN_DIM);
        uint2* __restrict__ w64 = (uint2*)buf0;
#pragma unroll
        for (int s = 0; s < SITER; ++s) {
            float4 v = xr[s * NT + t];
            uint2 h;
            h.x = pack2_f16(v.x, v.y);
            h.y = pack2_f16(v.z, v.w);
            w64[s * NT + t] = h;
        }
    }
    __syncthreads();

#pragma unroll
    for (int k = 0; k < RPB; ++k) {
        const uint16_t* __restrict__ cur = (k & 1) ? buf1 : buf0;
        uint16_t*       __restrict__ nxt = (k & 1) ? buf0 : buf1;

        // 1) issue prefetch loads for row k+1 FIRST (pinned by sched_barrier);
        //    their L3/HBM latency hides under the whole compute block below.
        float4 pf[SITER];
        if (k + 1 < RPB) {
            const float4* __restrict__ xr =
                (const float4*)(x + (size_t)(b + (k + 1) * GRID) * IN_DIM);
#pragma unroll
            for (int s = 0; s < SITER; ++s) pf[s] = xr[s * NT + t];
        }
        __builtin_amdgcn_sched_barrier(0);

        // 2) compute row k from cur; stores stream out while prefetch is in flight
        fvec4* __restrict__ o = (fvec4*)(out + (size_t)(b + k * GRID) * OUT_DIM);
#pragma unroll
        for (int i = 0; i < ITER; ++i) {
            const uint32_t w0 = p[i].x, w1 = p[i].y, w2 = p[i].z, w3 = p[i].w;
            // batch the 8 random LDS reads (independent -> pipelined)
            float a0 = ldrow(cur, w0 & 0xFFFEu), b0 = ldrow(cur, (w0 >> 16) & 0xFFFEu);
            float a1 = ldrow(cur, w1 & 0xFFFEu), b1 = ldrow(cur, (w1 >> 16) & 0xFFFEu);
            float a2 = ldrow(cur, w2 & 0xFFFEu), b2 = ldrow(cur, (w2 >> 16) & 0xFFFEu);
            float a3 = ldrow(cur, w3 & 0xFFFEu), b3 = ldrow(cur, (w3 >> 16) & 0xFFFEu);
            fvec4 res;
            res.x = sel(w0 & 1u, a0) * sel(w0 & 0x10000u, b0);
            res.y = sel(w1 & 1u, a1) * sel(w1 & 0x10000u, b1);
            res.z = sel(w2 & 1u, a2) * sel(w2 & 0x10000u, b2);
            res.w = sel(w3 & 1u, a3) * sel(w3 & 0x10000u, b3);
            __builtin_nontemporal_store(res, &o[i * NT + t]);   // out never re-read
        }

        // 3) convert + write row k+1 into nxt (waits only on pf loads; the wait
        //    lands after ~700cy of compute, so latency is fully hidden)
        if (k + 1 < RPB) {
            uint2* __restrict__ w64 = (uint2*)nxt;
#pragma unroll
            for (int s = 0; s < SITER; ++s) {
                uint2 h;
                h.x = pack2_f16(pf[s].x, pf[s].y);
                h.y = pack2_f16(pf[s].z, pf[s].w);
                w64[s * NT + t] = h;
            }
        }
        __syncthreads();   // nxt complete; cur free for overwrite next iter
    }
}

extern "C" void kernel_launch(void* const* d_in, const int* in_sizes, int n_in,
                              void* d_out, int out_size, void* d_ws, size_t ws_size,
                              hipStream_t stream) {
    const float* x      = (const float*)d_in[0];
    const float* logits = (const float*)d_in[1];
    const int*   idx_a  = (const int*)d_in[2];
    const int*   idx_b  = (const int*)d_in[3];
    uint32_t*    packed = (uint32_t*)d_ws;   // 128 KiB scratch
    float*       out    = (float*)d_out;

    // allow 128 KiB dynamic LDS (one block per CU); idempotent, not a stream op
    static bool lds_opt_in = false;
    if (!lds_opt_in) {
        (void)hipFuncSetAttribute(reinterpret_cast<const void*>(logic_gather),
                                  hipFuncAttributeMaxDynamicSharedMemorySize, LDS_BYTES);
        lds_opt_in = true;
    }

    hipLaunchKernelGGL(pack_meta, dim3(OUT_DIM / 256), dim3(256), 0, stream,
                       idx_a, idx_b, logits, packed);
    hipLaunchKernelGGL(logic_gather, dim3(GRID), dim3(NT), LDS_BYTES, stream,
                       x, packed, out);
}